// Round 1
// baseline (250.530 us; speedup 1.0000x reference)
//
#include <hip/hip_runtime.h>

#define EMB  256
#define NCLS 100
#define NB   64
#define NS   128
#define NL   64
#define CCH  10   // classes per block in kernel 2

// Kernel 1: sents[(b*NS+s)][e] = (1/NL) * sum_l emb[tok[b,s,l]][e]
// One block per sentence. 4 groups of 64 lanes, each group covers the full
// 256-float row via float4 and strides over tokens; partials combined in LDS.
__global__ __launch_bounds__(256) void k_gather_mean(
    const int* __restrict__ tok, const float* __restrict__ emb,
    float* __restrict__ sents)
{
    const int sid = blockIdx.x;          // 0 .. NB*NS-1
    const int tid = threadIdx.x;
    __shared__ int   toks[NL];
    __shared__ float part[4][EMB];

    if (tid < NL) toks[tid] = tok[(size_t)sid * NL + tid];
    __syncthreads();

    const int g    = tid >> 6;   // token-group 0..3
    const int lane = tid & 63;   // covers 256 floats as float4

    float4 acc = make_float4(0.f, 0.f, 0.f, 0.f);
    #pragma unroll
    for (int i = 0; i < NL / 4; ++i) {
        const int l = g + (i << 2);
        const float4* row = reinterpret_cast<const float4*>(emb + (size_t)toks[l] * EMB);
        float4 v = row[lane];                 // coalesced: 64 lanes x 16B = 1KB
        acc.x += v.x; acc.y += v.y; acc.z += v.z; acc.w += v.w;
    }
    reinterpret_cast<float4*>(&part[g][0])[lane] = acc;
    __syncthreads();

    const float ssum = part[0][tid] + part[1][tid] + part[2][tid] + part[3][tid];
    sents[(size_t)sid * EMB + tid] = ssum * (1.0f / NL);
}

// Kernel 2: logits[b,c] = sum_s softmax_s(ce[c].sents[b,s]) * (mw[c].sents[b,s]) + bias[c]
// Block = (b, chunk of CCH classes); 128 threads = one per sentence s.
__global__ __launch_bounds__(128) void k_attn_logits(
    const float* __restrict__ sents, const float* __restrict__ ce,
    const float* __restrict__ mw,    const float* __restrict__ bias,
    float* __restrict__ out)
{
    const int b  = blockIdx.x;
    const int c0 = blockIdx.y * CCH;
    const int s  = threadIdx.x;          // 0..127

    __shared__ float ce_l[CCH][EMB];
    __shared__ float mw_l[CCH][EMB];
    __shared__ float sc_l[CCH][NS];
    __shared__ float tv_l[CCH][NS];

    for (int i = s; i < CCH * EMB; i += 128) {
        const int c = i >> 8, e = i & (EMB - 1);
        ce_l[c][e] = ce[(size_t)(c0 + c) * EMB + e];
        mw_l[c][e] = mw[(size_t)(c0 + c) * EMB + e];
    }
    __syncthreads();

    float sc[CCH], tv[CCH];
    #pragma unroll
    for (int c = 0; c < CCH; ++c) { sc[c] = 0.f; tv[c] = 0.f; }

    const float* row = sents + ((size_t)b * NS + s) * EMB;
    for (int eb = 0; eb < EMB; eb += 64) {
        float4 r[16];
        #pragma unroll
        for (int i = 0; i < 16; ++i)
            r[i] = reinterpret_cast<const float4*>(row + eb)[i];
        #pragma unroll
        for (int c = 0; c < CCH; ++c) {
            float a = 0.f, t = 0.f;
            #pragma unroll
            for (int i = 0; i < 16; ++i) {
                const int e = eb + (i << 2);
                a += r[i].x * ce_l[c][e]     + r[i].y * ce_l[c][e + 1]
                   + r[i].z * ce_l[c][e + 2] + r[i].w * ce_l[c][e + 3];
                t += r[i].x * mw_l[c][e]     + r[i].y * mw_l[c][e + 1]
                   + r[i].z * mw_l[c][e + 2] + r[i].w * mw_l[c][e + 3];
            }
            sc[c] += a; tv[c] += t;
        }
    }

    #pragma unroll
    for (int c = 0; c < CCH; ++c) { sc_l[c][s] = sc[c]; tv_l[c][s] = tv[c]; }
    __syncthreads();

    // Softmax-weighted sum: each wave handles alternating classes.
    const int wid = s >> 6, lane = s & 63;
    for (int c = wid; c < CCH; c += 2) {
        const float x0 = sc_l[c][lane], x1 = sc_l[c][lane + 64];
        float m = fmaxf(x0, x1);
        #pragma unroll
        for (int d = 1; d < 64; d <<= 1) m = fmaxf(m, __shfl_xor(m, d));
        const float p0 = __expf(x0 - m), p1 = __expf(x1 - m);
        const float t0 = tv_l[c][lane],  t1 = tv_l[c][lane + 64];
        float sp = p0 + p1;
        float st = p0 * t0 + p1 * t1;
        #pragma unroll
        for (int d = 1; d < 64; d <<= 1) {
            sp += __shfl_xor(sp, d);
            st += __shfl_xor(st, d);
        }
        if (lane == 0)
            out[(size_t)b * NCLS + c0 + c] = st / sp + bias[c0 + c];
    }
}

extern "C" void kernel_launch(void* const* d_in, const int* in_sizes, int n_in,
                              void* d_out, int out_size, void* d_ws, size_t ws_size,
                              hipStream_t stream)
{
    const int*   tok  = (const int*)  d_in[0];   // (B,S,L) int32
    const float* emb  = (const float*)d_in[1];   // (VOCAB, EMB)
    const float* ce   = (const float*)d_in[2];   // (NCLS, EMB)
    const float* mw   = (const float*)d_in[3];   // (NCLS, EMB)
    const float* bias = (const float*)d_in[4];   // (NCLS, 1)
    float* out   = (float*)d_out;                // (B, NCLS)
    float* sents = (float*)d_ws;                 // NB*NS*EMB floats = 8 MB

    k_gather_mean<<<NB * NS, 256, 0, stream>>>(tok, emb, sents);
    k_attn_logits<<<dim3(NB, NCLS / CCH), 128, 0, stream>>>(sents, ce, mw, bias, out);
}